// Round 6
// baseline (284.031 us; speedup 1.0000x reference)
//
#include <hip/hip_runtime.h>
#include <math.h>

// ---------------------------------------------------------------------------
// GNNEncoder: 3x GCNConv(relu) -> sum of layers -> global_mean_pool -> MLP
// CSR via bucketed counting sort (block-contiguous writes). H stored bf16 in
// TWO channel-half slabs (N x 32 each, 3.2 MB -> fits one XCD L2). Aggs are
// split by half and routed to disjoint XCD sets via blockIdx%8, so each
// random gather is exactly ONE 64B line, L2-resident. col2 = (src, dis[src]).
// ---------------------------------------------------------------------------

__device__ inline float bf2f(unsigned short h) {
    return __uint_as_float((unsigned)h << 16);
}
__device__ inline float4 bh4f(ushort4 u) {
    return make_float4(bf2f(u.x), bf2f(u.y), bf2f(u.z), bf2f(u.w));
}
__device__ inline unsigned short f2bf(float f) {  // round-to-nearest-even
    unsigned u = __float_as_uint(f);
    return (unsigned short)((u + (0x7FFFu + ((u >> 16) & 1u))) >> 16);
}
__device__ inline float4 f4fma(float s, float4 a, float4 acc) {
    acc.x += s * a.x; acc.y += s * a.y; acc.z += s * a.z; acc.w += s * a.w;
    return acc;
}
__device__ inline float f4c(const float4& v, int k) {
    return k == 0 ? v.x : k == 1 ? v.y : k == 2 ? v.z : v.w;
}

// ---- pass A: coarse bucket hist (dst>>8) + per-node degree (global atomics)
__global__ void kA_hist(const int* __restrict__ dst, int* __restrict__ hist,
                        int* __restrict__ count, int E, int chunk) {
    __shared__ int h[256];
    int t = threadIdx.x;
    h[t] = 0;
    __syncthreads();
    int e0 = blockIdx.x * chunk;
    int e1 = min(e0 + chunk, E);
    for (int e = e0 + t; e < e1; e += 256) {
        int d = dst[e];
        atomicAdd(&h[d >> 8], 1);
        atomicAdd(&count[d], 1);
    }
    __syncthreads();
    hist[blockIdx.x * 256 + t] = h[t];
}

// block k scans column k of hist over chunk-blocks -> cursorA, tot; also dis
__global__ void kA_colscan(const int* __restrict__ hist, int* __restrict__ cursorA,
                           int* __restrict__ tot, const int* __restrict__ count,
                           float* __restrict__ dis, int N) {
    __shared__ int s[256];
    int t = threadIdx.x;
    int k = blockIdx.x;
    int v = hist[t * 256 + k];
    s[t] = v;
    __syncthreads();
    for (int st = 1; st < 256; st <<= 1) {
        int u = s[t];
        if (t >= st) u += s[t - st];
        __syncthreads();
        s[t] = u;
        __syncthreads();
    }
    cursorA[t * 256 + k] = s[t] - v;
    if (t == 255) tot[k] = s[255];
    int i = k * 256 + t;
    if (i < N) dis[i] = rsqrtf((float)(count[i] + 1));  // +1 self-loop
}

// scatter packed (dstLow<<24 | src) into bucket-contiguous ebuf (bstart inline)
__global__ void kA_scatter(const int* __restrict__ src, const int* __restrict__ dst,
                           const int* __restrict__ cursorA, const int* __restrict__ tot,
                           unsigned* __restrict__ ebuf, int E, int chunk) {
    __shared__ int s[256];
    __shared__ int cur[256];
    int t = threadIdx.x;
    s[t] = tot[t];
    __syncthreads();
    for (int st = 1; st < 256; st <<= 1) {
        int u = s[t];
        if (t >= st) u += s[t - st];
        __syncthreads();
        s[t] = u;
        __syncthreads();
    }
    int bstart = (t == 0) ? 0 : s[t - 1];
    cur[t] = cursorA[blockIdx.x * 256 + t] + bstart;
    __syncthreads();
    int e0 = blockIdx.x * chunk;
    int e1 = min(e0 + chunk, E);
    for (int e = e0 + t; e < e1; e += 256) {
        int d = dst[e];
        int p = atomicAdd(&cur[d >> 8], 1);
        ebuf[p] = ((unsigned)(d & 255) << 24) | (unsigned)src[e];
    }
}

// pass B fused: per-bucket degree hist -> offs; scatter col2 = (src, dis[src])
__global__ void kB(const unsigned* __restrict__ ebuf, const int* __restrict__ tot,
                   const float* __restrict__ dis, int* __restrict__ offs,
                   float2* __restrict__ col2, int N, int E) {
    __shared__ int s[256];
    __shared__ int h[256];
    __shared__ int cur[256];
    int t = threadIdx.x;
    int k = blockIdx.x;
    s[t] = tot[t];
    __syncthreads();
    for (int st = 1; st < 256; st <<= 1) {
        int u = s[t];
        if (t >= st) u += s[t - st];
        __syncthreads();
        s[t] = u;
        __syncthreads();
    }
    int lo = (k == 0) ? 0 : s[k - 1];
    int hi = s[k];
    h[t] = 0;
    __syncthreads();
    for (int p = lo + t; p < hi; p += 256) atomicAdd(&h[ebuf[p] >> 24], 1);
    __syncthreads();
    int c = h[t];
    s[t] = c;
    __syncthreads();
    for (int st = 1; st < 256; st <<= 1) {
        int u = s[t];
        if (t >= st) u += s[t - st];
        __syncthreads();
        s[t] = u;
        __syncthreads();
    }
    int start = lo + s[t] - c;
    cur[t] = start;
    int node = k * 256 + t;
    if (node < N) offs[node] = start;
    if (node == N - 1) offs[N] = E;
    __syncthreads();
    for (int p = lo + t; p < hi; p += 256) {
        unsigned e = ebuf[p];
        int srcI = (int)(e & 0x00FFFFFFu);
        int q = atomicAdd(&cur[e >> 24], 1);
        col2[q] = make_float2(__int_as_float(srcI), dis[srcI]);
    }
}

// ---- dense transform: 64 nodes/block, 4 nodes/thread; bf16 two-slab output -
template <int K>
__global__ void k_gemm(const float* __restrict__ X, const float* __restrict__ W,
                       unsigned short* __restrict__ H, int n) {
    __shared__ float4 w4[K * 16];
    int t = threadIdx.x;
    const float4* W4 = (const float4*)W;
    for (int i = t; i < K * 16; i += 256) w4[i] = W4[i];
    __syncthreads();
    int j4 = t & 15;
    int ng = t >> 4;
    int base = blockIdx.x * 64 + ng * 4;
    const float4* Xr[4];
#pragma unroll
    for (int m = 0; m < 4; m++) {
        int nm = min(base + m, n - 1);
        Xr[m] = (const float4*)(X + (size_t)nm * K);
    }
    float4 acc[4];
#pragma unroll
    for (int m = 0; m < 4; m++) acc[m] = make_float4(0.f, 0.f, 0.f, 0.f);
#pragma unroll 2
    for (int k0 = 0; k0 < K; k0 += 4) {
        float4 xv[4];
#pragma unroll
        for (int m = 0; m < 4; m++) xv[m] = Xr[m][k0 >> 2];
#pragma unroll
        for (int kk = 0; kk < 4; kk++) {
            float4 wv = w4[(k0 + kk) * 16 + j4];
#pragma unroll
            for (int m = 0; m < 4; m++) acc[m] = f4fma(f4c(xv[m], kk), wv, acc[m]);
        }
    }
    // two channel-half slabs: slab (j4>>3), within-slab ushort4 idx node*8+(j4&7)
    ushort4* slab = (ushort4*)H + (size_t)(j4 >> 3) * (size_t)n * 8;
#pragma unroll
    for (int m = 0; m < 4; m++)
        if (base + m < n) {
            ushort4 u;
            u.x = f2bf(acc[m].x); u.y = f2bf(acc[m].y);
            u.z = f2bf(acc[m].z); u.w = f2bf(acc[m].w);
            slab[(size_t)(base + m) * 8 + (j4 & 7)] = u;
        }
}

// Half-split aggregation: 32 nodes/block, 8 lanes x ushort4 (4ch) per node.
// Each gather = one 64B line from this half's 3.2MB slab (XCD-L2-resident via
// blockIdx%8 routing: blocks with (blockIdx%8)<4 do half 0, others half 1).
__global__ void k_agg(const unsigned short* __restrict__ H, const float2* __restrict__ col2,
                      const int* __restrict__ offs, const float* __restrict__ dis,
                      const float* __restrict__ bias, const float* __restrict__ add1,
                      const float* __restrict__ add2, float* __restrict__ Out,
                      int n, int tiles) {
    int B = blockIdx.x;
    int x = B & 7;
    int h = x >> 2;                       // 0 for XCDs 0-3, 1 for 4-7 (heuristic)
    int within = (B >> 3) * 4 + (x & 3);  // tile index inside this half
    if (within >= tiles) return;
    int t = threadIdx.x;
    int node = within * 32 + (t >> 3);
    if (node >= n) return;
    int lane = t & 7;  // 4 channels each
    const ushort4* H4 = (const ushort4*)H + (size_t)h * (size_t)n * 8;
    float dn = dis[node];
    float4 acc = bh4f(H4[(size_t)node * 8 + lane]);
    acc.x *= dn; acc.y *= dn; acc.z *= dn; acc.w *= dn;
    int lo = offs[node], hi = offs[node + 1];
    int p = lo;
    for (; p + 4 <= hi; p += 4) {
        float2 e0 = col2[p], e1 = col2[p + 1], e2 = col2[p + 2], e3 = col2[p + 3];
        float4 h0 = bh4f(H4[(size_t)__float_as_int(e0.x) * 8 + lane]);
        float4 h1 = bh4f(H4[(size_t)__float_as_int(e1.x) * 8 + lane]);
        float4 h2 = bh4f(H4[(size_t)__float_as_int(e2.x) * 8 + lane]);
        float4 h3 = bh4f(H4[(size_t)__float_as_int(e3.x) * 8 + lane]);
        acc = f4fma(e0.y, h0, acc);
        acc = f4fma(e1.y, h1, acc);
        acc = f4fma(e2.y, h2, acc);
        acc = f4fma(e3.y, h3, acc);
    }
    for (; p < hi; p++) {
        float2 e = col2[p];
        acc = f4fma(e.y, bh4f(H4[(size_t)__float_as_int(e.x) * 8 + lane]), acc);
    }
    float4 b = ((const float4*)bias)[h * 8 + lane];
    float4 v;
    v.x = fmaxf(acc.x * dn + b.x, 0.f);
    v.y = fmaxf(acc.y * dn + b.y, 0.f);
    v.z = fmaxf(acc.z * dn + b.z, 0.f);
    v.w = fmaxf(acc.w * dn + b.w, 0.f);
    size_t oi = (size_t)node * 16 + h * 8 + lane;
    if (add1) {
        float4 a1 = ((const float4*)add1)[oi];
        float4 a2 = ((const float4*)add2)[oi];
        v.x += a1.x + a2.x; v.y += a1.y + a2.y; v.z += a1.z + a2.z; v.w += a1.w + a2.w;
    }
    ((float4*)Out)[oi] = v;
}

// one 64-thread block per graph: segment mean (sorted batch) + MLP head
__global__ void k_poolhead(const float* __restrict__ S, const int* __restrict__ batch,
                           const float* __restrict__ Wp1, const float* __restrict__ bp1,
                           const float* __restrict__ Wp2, const float* __restrict__ bp2,
                           float* __restrict__ out, int n, int G) {
    int g = blockIdx.x;
    int j = threadIdx.x;  // 0..63
    int a = 0, b = n;
    while (a < b) { int m = (a + b) >> 1; if (batch[m] < g) a = m + 1; else b = m; }
    int beg = a;
    b = n;
    while (a < b) { int m = (a + b) >> 1; if (batch[m] < g + 1) a = m + 1; else b = m; }
    int end = a;
    float sum = 0.f;
    int i = beg;
    for (; i + 2 <= end; i += 2)
        sum += S[(size_t)i * 64 + j] + S[(size_t)(i + 1) * 64 + j];
    if (i < end) sum += S[(size_t)i * 64 + j];
    float cnt = (float)(end - beg);
    float p = sum / fmaxf(cnt, 1.f);
    __shared__ float ps[64];
    __shared__ float ts[64];
    ps[j] = p;
    __syncthreads();
    float t1 = bp1[j];
#pragma unroll 8
    for (int k = 0; k < 64; k++) t1 += ps[k] * Wp1[k * 64 + j];
    t1 = fmaxf(t1, 0.f);
    ts[j] = t1;
    __syncthreads();
    if (j < 32) {
        float o = bp2[j];
#pragma unroll 8
        for (int k = 0; k < 64; k++) o += ts[k] * Wp2[k * 32 + j];
        out[(size_t)g * 32 + j] = o;
    }
}

extern "C" void kernel_launch(void* const* d_in, const int* in_sizes, int n_in,
                              void* d_out, int out_size, void* d_ws, size_t ws_size,
                              hipStream_t stream) {
    const float* x   = (const float*)d_in[0];
    const int*   ei  = (const int*)d_in[1];
    const int*   bat = (const int*)d_in[2];
    const float* W1  = (const float*)d_in[3];
    const float* b1  = (const float*)d_in[4];
    const float* W2  = (const float*)d_in[5];
    const float* b2  = (const float*)d_in[6];
    const float* W3  = (const float*)d_in[7];
    const float* b3  = (const float*)d_in[8];
    const float* Wp1 = (const float*)d_in[9];
    const float* bp1 = (const float*)d_in[10];
    const float* Wp2 = (const float*)d_in[11];
    const float* bp2 = (const float*)d_in[12];

    int N = in_sizes[0] / 128;
    int E = in_sizes[1] / 2;
    int G = out_size / 32;
    const int* src = ei;
    const int* dst = ei + E;

    char* w = (char*)d_ws;
    auto alloc = [&](size_t bytes) -> void* {
        void* p = (void*)w;
        w += (bytes + 255) & ~(size_t)255;
        return p;
    };
    int NB = (N + 255) / 256;  // buckets (<=256)
    int*            count   = (int*)alloc((size_t)N * 4);
    int*            offs    = (int*)alloc((size_t)(N + 1) * 4);
    float2*         col2    = (float2*)alloc((size_t)E * 8);
    float*          dis     = (float*)alloc((size_t)N * 4);
    int*            hist    = (int*)alloc((size_t)256 * 256 * 4);
    int*            cursorA = (int*)alloc((size_t)256 * 256 * 4);
    int*            tot     = (int*)alloc((size_t)256 * 4);
    unsigned*       ebuf    = (unsigned*)alloc((size_t)E * 4);
    unsigned short* Hb      = (unsigned short*)alloc((size_t)N * 64 * 2);
    float*          X1      = (float*)alloc((size_t)N * 64 * 4);
    float*          X2      = (float*)alloc((size_t)N * 64 * 4);
    float*          S       = (float*)alloc((size_t)N * 64 * 4);

    int chunk = (E + 255) / 256;

    hipMemsetAsync(count, 0, (size_t)N * 4, stream);
    kA_hist<<<256, 256, 0, stream>>>(dst, hist, count, E, chunk);
    kA_colscan<<<256, 256, 0, stream>>>(hist, cursorA, tot, count, dis, N);
    kA_scatter<<<256, 256, 0, stream>>>(src, dst, cursorA, tot, ebuf, E, chunk);
    kB<<<NB, 256, 0, stream>>>(ebuf, tot, dis, offs, col2, N, E);

    int NB64 = (N + 63) / 64;
    int tiles = (N + 31) / 32;
    int gagg = ((tiles + 3) / 4) * 8;  // both halves fully covered
    k_gemm<128><<<NB64, 256, 0, stream>>>(x, W1, Hb, N);
    k_agg<<<gagg, 256, 0, stream>>>(Hb, col2, offs, dis, b1, nullptr, nullptr, X1, N, tiles);
    k_gemm<64><<<NB64, 256, 0, stream>>>(X1, W2, Hb, N);
    k_agg<<<gagg, 256, 0, stream>>>(Hb, col2, offs, dis, b2, nullptr, nullptr, X2, N, tiles);
    k_gemm<64><<<NB64, 256, 0, stream>>>(X2, W3, Hb, N);
    k_agg<<<gagg, 256, 0, stream>>>(Hb, col2, offs, dis, b3, X1, X2, S, N, tiles);

    k_poolhead<<<G, 64, 0, stream>>>(S, bat, Wp1, bp1, Wp2, bp2, (float*)d_out, N, G);
}

// Round 7
// 283.719 us; speedup vs baseline: 1.0011x; 1.0011x over previous
//
#include <hip/hip_runtime.h>
#include <math.h>

// ---------------------------------------------------------------------------
// GNNEncoder: 3x GCNConv(relu) -> sum of layers -> global_mean_pool -> MLP
// CSR via bucketed counting sort. H bf16 in two channel-half slabs (Nx32).
// Dense transforms on MFMA 16x16x32 bf16 (A = W^T from LDS, B = X^T cast
// in-register, D[ch][node] -> ushort4 slab stores). Aggs gather 1 line/edge.
// ---------------------------------------------------------------------------

typedef short short8 __attribute__((ext_vector_type(8)));
typedef float f32x4 __attribute__((ext_vector_type(4)));

__device__ inline float bf2f(unsigned short h) {
    return __uint_as_float((unsigned)h << 16);
}
__device__ inline float4 bh4f(ushort4 u) {
    return make_float4(bf2f(u.x), bf2f(u.y), bf2f(u.z), bf2f(u.w));
}
__device__ inline unsigned short f2bf(float f) {  // round-to-nearest-even
    unsigned u = __float_as_uint(f);
    return (unsigned short)((u + (0x7FFFu + ((u >> 16) & 1u))) >> 16);
}
__device__ inline float4 f4fma(float s, float4 a, float4 acc) {
    acc.x += s * a.x; acc.y += s * a.y; acc.z += s * a.z; acc.w += s * a.w;
    return acc;
}

// ---- pass A: coarse bucket hist (dst>>8) + per-node degree (global atomics)
__global__ void kA_hist(const int* __restrict__ dst, int* __restrict__ hist,
                        int* __restrict__ count, int E, int chunk) {
    __shared__ int h[256];
    int t = threadIdx.x;
    h[t] = 0;
    __syncthreads();
    int e0 = blockIdx.x * chunk;
    int e1 = min(e0 + chunk, E);
    for (int e = e0 + t; e < e1; e += 256) {
        int d = dst[e];
        atomicAdd(&h[d >> 8], 1);
        atomicAdd(&count[d], 1);
    }
    __syncthreads();
    hist[blockIdx.x * 256 + t] = h[t];
}

// block k scans column k of hist over chunk-blocks -> cursorA, tot; also dis
__global__ void kA_colscan(const int* __restrict__ hist, int* __restrict__ cursorA,
                           int* __restrict__ tot, const int* __restrict__ count,
                           float* __restrict__ dis, int N) {
    __shared__ int s[256];
    int t = threadIdx.x;
    int k = blockIdx.x;
    int v = hist[t * 256 + k];
    s[t] = v;
    __syncthreads();
    for (int st = 1; st < 256; st <<= 1) {
        int u = s[t];
        if (t >= st) u += s[t - st];
        __syncthreads();
        s[t] = u;
        __syncthreads();
    }
    cursorA[t * 256 + k] = s[t] - v;
    if (t == 255) tot[k] = s[255];
    int i = k * 256 + t;
    if (i < N) dis[i] = rsqrtf((float)(count[i] + 1));  // +1 self-loop
}

// scatter packed (dstLow<<24 | src) into bucket-contiguous ebuf (bstart inline)
__global__ void kA_scatter(const int* __restrict__ src, const int* __restrict__ dst,
                           const int* __restrict__ cursorA, const int* __restrict__ tot,
                           unsigned* __restrict__ ebuf, int E, int chunk) {
    __shared__ int s[256];
    __shared__ int cur[256];
    int t = threadIdx.x;
    s[t] = tot[t];
    __syncthreads();
    for (int st = 1; st < 256; st <<= 1) {
        int u = s[t];
        if (t >= st) u += s[t - st];
        __syncthreads();
        s[t] = u;
        __syncthreads();
    }
    int bstart = (t == 0) ? 0 : s[t - 1];
    cur[t] = cursorA[blockIdx.x * 256 + t] + bstart;
    __syncthreads();
    int e0 = blockIdx.x * chunk;
    int e1 = min(e0 + chunk, E);
    for (int e = e0 + t; e < e1; e += 256) {
        int d = dst[e];
        int p = atomicAdd(&cur[d >> 8], 1);
        ebuf[p] = ((unsigned)(d & 255) << 24) | (unsigned)src[e];
    }
}

// pass B fused: per-bucket degree hist -> offs; scatter col2 = (src, dis[src])
__global__ void kB(const unsigned* __restrict__ ebuf, const int* __restrict__ tot,
                   const float* __restrict__ dis, int* __restrict__ offs,
                   float2* __restrict__ col2, int N, int E) {
    __shared__ int s[256];
    __shared__ int h[256];
    __shared__ int cur[256];
    int t = threadIdx.x;
    int k = blockIdx.x;
    s[t] = tot[t];
    __syncthreads();
    for (int st = 1; st < 256; st <<= 1) {
        int u = s[t];
        if (t >= st) u += s[t - st];
        __syncthreads();
        s[t] = u;
        __syncthreads();
    }
    int lo = (k == 0) ? 0 : s[k - 1];
    int hi = s[k];
    h[t] = 0;
    __syncthreads();
    for (int p = lo + t; p < hi; p += 256) atomicAdd(&h[ebuf[p] >> 24], 1);
    __syncthreads();
    int c = h[t];
    s[t] = c;
    __syncthreads();
    for (int st = 1; st < 256; st <<= 1) {
        int u = s[t];
        if (t >= st) u += s[t - st];
        __syncthreads();
        s[t] = u;
        __syncthreads();
    }
    int start = lo + s[t] - c;
    cur[t] = start;
    int node = k * 256 + t;
    if (node < N) offs[node] = start;
    if (node == N - 1) offs[N] = E;
    __syncthreads();
    for (int p = lo + t; p < hi; p += 256) {
        unsigned e = ebuf[p];
        int srcI = (int)(e & 0x00FFFFFFu);
        int q = atomicAdd(&cur[e >> 24], 1);
        col2[q] = make_float2(__int_as_float(srcI), dis[srcI]);
    }
}

// ---- MFMA dense transform: D[ch][node] = sum_k W[k][ch] * X[node][k] -------
// One wave per 16-node tile; A = W^T (bf16, LDS), B = X^T (bf16 from fp32).
// C layout: col(lane&15)=node, row(quad*4+reg)=channel -> ushort4 slab stores.
template <int K>
__global__ __launch_bounds__(256) void k_gemm_mfma(const float* __restrict__ X,
                                                   const float* __restrict__ W,
                                                   unsigned short* __restrict__ H, int n) {
    __shared__ short wt[64 * K];  // W^T[ch][k] bf16
    int t = threadIdx.x;
    for (int idx = t; idx < 64 * K; idx += 256) {
        int k = idx >> 6, ch = idx & 63;
        wt[ch * K + k] = (short)f2bf(W[idx]);
    }
    __syncthreads();
    int wave = t >> 6, lane = t & 63;
    int q = lane >> 4, l = lane & 15;
    int tile = blockIdx.x * 4 + wave;
    if (tile * 16 >= n) return;  // n % 16 == 0 -> whole tiles only
    int node = tile * 16 + l;
    // A-frags (weights): afr[mb][s] = W^T[mb*16+l][s*32 + q*8 .. +7]
    short8 afr[4][K / 32];
#pragma unroll
    for (int mb = 0; mb < 4; mb++)
#pragma unroll
        for (int s = 0; s < K / 32; s++)
            afr[mb][s] = *(const short8*)(wt + (mb * 16 + l) * K + s * 32 + q * 8);
    f32x4 acc[4] = {};
    const float* xr = X + (size_t)node * K + q * 8;
#pragma unroll
    for (int s = 0; s < K / 32; s++) {
        float4 xa = *(const float4*)(xr + s * 32);
        float4 xb = *(const float4*)(xr + s * 32 + 4);
        short8 bfr;
        bfr[0] = (short)f2bf(xa.x); bfr[1] = (short)f2bf(xa.y);
        bfr[2] = (short)f2bf(xa.z); bfr[3] = (short)f2bf(xa.w);
        bfr[4] = (short)f2bf(xb.x); bfr[5] = (short)f2bf(xb.y);
        bfr[6] = (short)f2bf(xb.z); bfr[7] = (short)f2bf(xb.w);
#pragma unroll
        for (int mb = 0; mb < 4; mb++)
            acc[mb] = __builtin_amdgcn_mfma_f32_16x16x32_bf16(afr[mb][s], bfr, acc[mb], 0, 0, 0);
    }
#pragma unroll
    for (int mb = 0; mb < 4; mb++) {
        ushort4 u;
        u.x = f2bf(acc[mb][0]); u.y = f2bf(acc[mb][1]);
        u.z = f2bf(acc[mb][2]); u.w = f2bf(acc[mb][3]);
        ushort4* slab = (ushort4*)H + (size_t)(mb >> 1) * (size_t)n * 8;
        slab[(size_t)node * 8 + (mb & 1) * 4 + q] = u;
    }
}

// Half-split aggregation: 32 nodes/block, 8 lanes x ushort4 (4ch) per node.
__global__ void k_agg(const unsigned short* __restrict__ H, const float2* __restrict__ col2,
                      const int* __restrict__ offs, const float* __restrict__ dis,
                      const float* __restrict__ bias, const float* __restrict__ add1,
                      const float* __restrict__ add2, float* __restrict__ Out,
                      int n, int tiles) {
    int B = blockIdx.x;
    int x = B & 7;
    int h = x >> 2;
    int within = (B >> 3) * 4 + (x & 3);
    if (within >= tiles) return;
    int t = threadIdx.x;
    int node = within * 32 + (t >> 3);
    if (node >= n) return;
    int lane = t & 7;
    const ushort4* H4 = (const ushort4*)H + (size_t)h * (size_t)n * 8;
    float dn = dis[node];
    float4 acc = bh4f(H4[(size_t)node * 8 + lane]);
    acc.x *= dn; acc.y *= dn; acc.z *= dn; acc.w *= dn;
    int lo = offs[node], hi = offs[node + 1];
    int p = lo;
    for (; p + 4 <= hi; p += 4) {
        float2 e0 = col2[p], e1 = col2[p + 1], e2 = col2[p + 2], e3 = col2[p + 3];
        float4 h0 = bh4f(H4[(size_t)__float_as_int(e0.x) * 8 + lane]);
        float4 h1 = bh4f(H4[(size_t)__float_as_int(e1.x) * 8 + lane]);
        float4 h2 = bh4f(H4[(size_t)__float_as_int(e2.x) * 8 + lane]);
        float4 h3 = bh4f(H4[(size_t)__float_as_int(e3.x) * 8 + lane]);
        acc = f4fma(e0.y, h0, acc);
        acc = f4fma(e1.y, h1, acc);
        acc = f4fma(e2.y, h2, acc);
        acc = f4fma(e3.y, h3, acc);
    }
    for (; p < hi; p++) {
        float2 e = col2[p];
        acc = f4fma(e.y, bh4f(H4[(size_t)__float_as_int(e.x) * 8 + lane]), acc);
    }
    float4 b = ((const float4*)bias)[h * 8 + lane];
    float4 v;
    v.x = fmaxf(acc.x * dn + b.x, 0.f);
    v.y = fmaxf(acc.y * dn + b.y, 0.f);
    v.z = fmaxf(acc.z * dn + b.z, 0.f);
    v.w = fmaxf(acc.w * dn + b.w, 0.f);
    size_t oi = (size_t)node * 16 + h * 8 + lane;
    if (add1) {
        float4 a1 = ((const float4*)add1)[oi];
        float4 a2 = ((const float4*)add2)[oi];
        v.x += a1.x + a2.x; v.y += a1.y + a2.y; v.z += a1.z + a2.z; v.w += a1.w + a2.w;
    }
    ((float4*)Out)[oi] = v;
}

// one 64-thread block per graph: segment mean (sorted batch) + MLP head
__global__ void k_poolhead(const float* __restrict__ S, const int* __restrict__ batch,
                           const float* __restrict__ Wp1, const float* __restrict__ bp1,
                           const float* __restrict__ Wp2, const float* __restrict__ bp2,
                           float* __restrict__ out, int n, int G) {
    int g = blockIdx.x;
    int j = threadIdx.x;  // 0..63
    int a = 0, b = n;
    while (a < b) { int m = (a + b) >> 1; if (batch[m] < g) a = m + 1; else b = m; }
    int beg = a;
    b = n;
    while (a < b) { int m = (a + b) >> 1; if (batch[m] < g + 1) a = m + 1; else b = m; }
    int end = a;
    float sum = 0.f;
    int i = beg;
    for (; i + 2 <= end; i += 2)
        sum += S[(size_t)i * 64 + j] + S[(size_t)(i + 1) * 64 + j];
    if (i < end) sum += S[(size_t)i * 64 + j];
    float cnt = (float)(end - beg);
    float p = sum / fmaxf(cnt, 1.f);
    __shared__ float ps[64];
    __shared__ float ts[64];
    ps[j] = p;
    __syncthreads();
    float t1 = bp1[j];
#pragma unroll 8
    for (int k = 0; k < 64; k++) t1 += ps[k] * Wp1[k * 64 + j];
    t1 = fmaxf(t1, 0.f);
    ts[j] = t1;
    __syncthreads();
    if (j < 32) {
        float o = bp2[j];
#pragma unroll 8
        for (int k = 0; k < 64; k++) o += ts[k] * Wp2[k * 32 + j];
        out[(size_t)g * 32 + j] = o;
    }
}

extern "C" void kernel_launch(void* const* d_in, const int* in_sizes, int n_in,
                              void* d_out, int out_size, void* d_ws, size_t ws_size,
                              hipStream_t stream) {
    const float* x   = (const float*)d_in[0];
    const int*   ei  = (const int*)d_in[1];
    const int*   bat = (const int*)d_in[2];
    const float* W1  = (const float*)d_in[3];
    const float* b1  = (const float*)d_in[4];
    const float* W2  = (const float*)d_in[5];
    const float* b2  = (const float*)d_in[6];
    const float* W3  = (const float*)d_in[7];
    const float* b3  = (const float*)d_in[8];
    const float* Wp1 = (const float*)d_in[9];
    const float* bp1 = (const float*)d_in[10];
    const float* Wp2 = (const float*)d_in[11];
    const float* bp2 = (const float*)d_in[12];

    int N = in_sizes[0] / 128;
    int E = in_sizes[1] / 2;
    int G = out_size / 32;
    const int* src = ei;
    const int* dst = ei + E;

    char* w = (char*)d_ws;
    auto alloc = [&](size_t bytes) -> void* {
        void* p = (void*)w;
        w += (bytes + 255) & ~(size_t)255;
        return p;
    };
    int NB = (N + 255) / 256;  // buckets (<=256)
    int*            count   = (int*)alloc((size_t)N * 4);
    int*            offs    = (int*)alloc((size_t)(N + 1) * 4);
    float2*         col2    = (float2*)alloc((size_t)E * 8);
    float*          dis     = (float*)alloc((size_t)N * 4);
    int*            hist    = (int*)alloc((size_t)256 * 256 * 4);
    int*            cursorA = (int*)alloc((size_t)256 * 256 * 4);
    int*            tot     = (int*)alloc((size_t)256 * 4);
    unsigned*       ebuf    = (unsigned*)alloc((size_t)E * 4);
    unsigned short* Hb      = (unsigned short*)alloc((size_t)N * 64 * 2);
    float*          X1      = (float*)alloc((size_t)N * 64 * 4);
    float*          X2      = (float*)alloc((size_t)N * 64 * 4);
    float*          S       = (float*)alloc((size_t)N * 64 * 4);

    int chunk = (E + 255) / 256;

    hipMemsetAsync(count, 0, (size_t)N * 4, stream);
    kA_hist<<<256, 256, 0, stream>>>(dst, hist, count, E, chunk);
    kA_colscan<<<256, 256, 0, stream>>>(hist, cursorA, tot, count, dis, N);
    kA_scatter<<<256, 256, 0, stream>>>(src, dst, cursorA, tot, ebuf, E, chunk);
    kB<<<NB, 256, 0, stream>>>(ebuf, tot, dis, offs, col2, N, E);

    int gtiles = (N + 15) / 16;          // 16-node MFMA tiles (N%16==0 here)
    int ggemm  = (gtiles + 3) / 4;       // 4 waves per block
    int tiles  = (N + 31) / 32;          // agg tiles
    int gagg   = ((tiles + 3) / 4) * 8;  // both halves covered
    k_gemm_mfma<128><<<ggemm, 256, 0, stream>>>(x, W1, Hb, N);
    k_agg<<<gagg, 256, 0, stream>>>(Hb, col2, offs, dis, b1, nullptr, nullptr, X1, N, tiles);
    k_gemm_mfma<64><<<ggemm, 256, 0, stream>>>(X1, W2, Hb, N);
    k_agg<<<gagg, 256, 0, stream>>>(Hb, col2, offs, dis, b2, nullptr, nullptr, X2, N, tiles);
    k_gemm_mfma<64><<<ggemm, 256, 0, stream>>>(X2, W3, Hb, N);
    k_agg<<<gagg, 256, 0, stream>>>(Hb, col2, offs, dis, b3, X1, X2, S, N, tiles);

    k_poolhead<<<G, 64, 0, stream>>>(S, bat, Wp1, bp1, Wp2, bp2, (float*)d_out, N, G);
}